// Round 1
// baseline (754.577 us; speedup 1.0000x reference)
//
#include <hip/hip_runtime.h>
#include <math.h>

#define N 8192
#define D 256
#define MARGIN 0.3f
#define EPS 1e-12f

#define JSPLIT 8          // j-range splits -> grid = 128*8 = 1024 blocks
#define TILE 64           // i-tile and j-tile
#define KC 64             // K chunk staged in LDS
#define LSTR 68           // LDS row stride in floats (pad: bank-conflict-free, 16B aligned)

// ---------------- Kernel 1: L2 normalize rows, record sq = sum(f*f) ----------------
__global__ __launch_bounds__(256) void normalize_kernel(const float* __restrict__ x,
                                                        float* __restrict__ fn,
                                                        float* __restrict__ sq) {
    const int row  = blockIdx.x * 4 + (threadIdx.x >> 6);   // 1 wave per row
    const int lane = threadIdx.x & 63;
    float4 v = ((const float4*)(x + (size_t)row * D))[lane];
    float s = v.x * v.x + v.y * v.y + v.z * v.z + v.w * v.w;
    #pragma unroll
    for (int off = 32; off; off >>= 1) s += __shfl_down(s, off);
    s = __shfl(s, 0);
    const float inv = 1.0f / fmaxf(sqrtf(s), 1e-12f);
    v.x *= inv; v.y *= inv; v.z *= inv; v.w *= inv;
    ((float4*)(fn + (size_t)row * D))[lane] = v;
    // sq computed on normalized values, matching reference rounding behavior
    float s2 = v.x * v.x + v.y * v.y + v.z * v.z + v.w * v.w;
    #pragma unroll
    for (int off = 32; off; off >>= 1) s2 += __shfl_down(s2, off);
    if (lane == 0) sq[row] = s2;
}

// ---------------- Kernel 2: fused gram + batch-hard partial reductions ----------------
__global__ __launch_bounds__(256) void main_kernel(const float* __restrict__ fn,
                                                   const float* __restrict__ sq,
                                                   const int* __restrict__ lab,
                                                   float* __restrict__ hp_part,
                                                   float* __restrict__ hn_part) {
    __shared__ float As[KC][LSTR];     // transposed: As[k][i_local]
    __shared__ float Bs[KC][LSTR];     // transposed: Bs[k][j_local]
    __shared__ float red[TILE][17];    // cross-thread hp/hn reduction

    const int ib = blockIdx.x / JSPLIT;           // 0..127
    const int js = blockIdx.x % JSPLIT;           // 0..7
    const int i0 = ib * TILE;
    const int jbeg = js * (N / JSPLIT);
    const int jend = jbeg + (N / JSPLIT);

    const int t  = threadIdx.x;
    const int ti = t >> 4;     // 0..15  (i micro-tile /4)
    const int tj = t & 15;     // 0..15  (j micro-tile /4)

    float sqi[4]; int labi[4]; float hp[4], hn[4];
    #pragma unroll
    for (int ii = 0; ii < 4; ii++) {
        const int i = i0 + ti * 4 + ii;
        sqi[ii]  = sq[i];
        labi[ii] = lab[i];
        hp[ii] = 0.0f;                 // matches max(dist * mask): masked -> 0
        hn[ii] = INFINITY;
    }

    for (int jt = jbeg; jt < jend; jt += TILE) {
        float acc[4][4];
        #pragma unroll
        for (int ii = 0; ii < 4; ii++)
            #pragma unroll
            for (int jj = 0; jj < 4; jj++) acc[ii][jj] = 0.0f;

        for (int kc = 0; kc < D; kc += KC) {
            __syncthreads();   // protect LDS from previous chunk/tile consumers
            // stage A and B chunks, transposed into [k][row] layout
            #pragma unroll
            for (int it = 0; it < 4; it++) {
                const int lin = t + 256 * it;      // 0..1023
                const int c4  = lin & 15;          // float4 column within chunk
                const int r   = lin >> 4;          // 0..63 local row
                const float4 a = *(const float4*)(fn + (size_t)(i0 + r) * D + kc + c4 * 4);
                const float4 b = *(const float4*)(fn + (size_t)(jt + r) * D + kc + c4 * 4);
                As[c4 * 4 + 0][r] = a.x; As[c4 * 4 + 1][r] = a.y;
                As[c4 * 4 + 2][r] = a.z; As[c4 * 4 + 3][r] = a.w;
                Bs[c4 * 4 + 0][r] = b.x; Bs[c4 * 4 + 1][r] = b.y;
                Bs[c4 * 4 + 2][r] = b.z; Bs[c4 * 4 + 3][r] = b.w;
            }
            __syncthreads();
            #pragma unroll 8
            for (int k = 0; k < KC; k++) {
                const float4 av = *(const float4*)(&As[k][ti * 4]);
                const float4 bv = *(const float4*)(&Bs[k][tj * 4]);
                const float ar[4] = {av.x, av.y, av.z, av.w};
                const float br[4] = {bv.x, bv.y, bv.z, bv.w};
                #pragma unroll
                for (int ii = 0; ii < 4; ii++)
                    #pragma unroll
                    for (int jj = 0; jj < 4; jj++)
                        acc[ii][jj] = fmaf(ar[ii], br[jj], acc[ii][jj]);
            }
        }

        // fused epilogue: distance + label mask + running hardest pos/neg
        float sqj[4]; int labj[4];
        #pragma unroll
        for (int jj = 0; jj < 4; jj++) {
            const int j = jt + tj * 4 + jj;
            sqj[jj]  = sq[j];
            labj[jj] = lab[j];
        }
        #pragma unroll
        for (int ii = 0; ii < 4; ii++) {
            #pragma unroll
            for (int jj = 0; jj < 4; jj++) {
                const float d2 = sqi[ii] + sqj[jj] - 2.0f * acc[ii][jj];
                const float dd = sqrtf(fmaxf(d2, EPS));
                const bool same = (labi[ii] == labj[jj]);
                hp[ii] = fmaxf(hp[ii], same ? dd : 0.0f);
                hn[ii] = fminf(hn[ii], same ? INFINITY : dd);
            }
        }
    }

    // reduce hp/hn across the 16 threads (tj) sharing each i-row
    __syncthreads();
    #pragma unroll
    for (int ii = 0; ii < 4; ii++) red[ti * 4 + ii][tj] = hp[ii];
    __syncthreads();
    if (t < TILE) {
        float v = red[t][0];
        #pragma unroll
        for (int q = 1; q < 16; q++) v = fmaxf(v, red[t][q]);
        hp_part[(size_t)js * N + i0 + t] = v;
    }
    __syncthreads();
    #pragma unroll
    for (int ii = 0; ii < 4; ii++) red[ti * 4 + ii][tj] = hn[ii];
    __syncthreads();
    if (t < TILE) {
        float v = red[t][0];
        #pragma unroll
        for (int q = 1; q < 16; q++) v = fminf(v, red[t][q]);
        hn_part[(size_t)js * N + i0 + t] = v;
    }
}

// ---------------- Kernel 3: combine splits, relu, mean ----------------
__global__ __launch_bounds__(256) void finalize_kernel(const float* __restrict__ hp_part,
                                                       const float* __restrict__ hn_part,
                                                       float* __restrict__ out) {
    const int t = threadIdx.x;
    float sum = 0.0f;
    for (int i = t; i < N; i += 256) {
        float hp = hp_part[i];
        float hn = hn_part[i];
        #pragma unroll
        for (int s = 1; s < JSPLIT; s++) {
            hp = fmaxf(hp, hp_part[(size_t)s * N + i]);
            hn = fminf(hn, hn_part[(size_t)s * N + i]);
        }
        const float l = hp - hn + MARGIN;
        sum += (l > 0.0f) ? l : 0.0f;
    }
    #pragma unroll
    for (int off = 32; off; off >>= 1) sum += __shfl_down(sum, off);
    __shared__ float ws[4];
    if ((t & 63) == 0) ws[t >> 6] = sum;
    __syncthreads();
    if (t == 0) out[0] = (ws[0] + ws[1] + ws[2] + ws[3]) * (1.0f / (float)N);
}

extern "C" void kernel_launch(void* const* d_in, const int* in_sizes, int n_in,
                              void* d_out, int out_size, void* d_ws, size_t ws_size,
                              hipStream_t stream) {
    const float* x   = (const float*)d_in[0];
    const int*   lab = (const int*)d_in[1];
    float* out = (float*)d_out;

    char* ws = (char*)d_ws;
    float* fn = (float*)ws;                                        // N*D floats
    float* sq = (float*)(ws + (size_t)N * D * 4);                  // N floats
    float* hp = (float*)(ws + (size_t)N * D * 4 + (size_t)N * 4);  // JSPLIT*N
    float* hn = hp + (size_t)JSPLIT * N;                           // JSPLIT*N

    normalize_kernel<<<N / 4, 256, 0, stream>>>(x, fn, sq);
    main_kernel<<<(N / TILE) * JSPLIT, 256, 0, stream>>>(fn, sq, lab, hp, hn);
    finalize_kernel<<<1, 256, 0, stream>>>(hp, hn, out);
}

// Round 2
// 167.283 us; speedup vs baseline: 4.5108x; 4.5108x over previous
//
#include <hip/hip_runtime.h>
#include <hip/hip_bf16.h>
#include <math.h>

#define N 8192
#define D 256
#define MARGIN 0.3f
#define EPS 1e-12f

#define BT 128            // block tile (i and j)
#define BK 64             // K chunk staged in LDS
#define LSTR 72           // LDS row stride in bf16 elements (pad 8: 16B-aligned, low conflicts)
#define NJB (N / BT)      // 64 j-blocks

typedef __attribute__((ext_vector_type(8))) short short8;   // 8 bf16 in 4 VGPRs
typedef __attribute__((ext_vector_type(4))) float floatx4;  // MFMA C/D

static __device__ inline ushort f2bf(float f) {
    __hip_bfloat16 h = __float2bfloat16(f);
    return *reinterpret_cast<ushort*>(&h);
}

// ---------------- Kernel 1: L2 normalize rows -> bf16 copy + fp32 sq ----------------
__global__ __launch_bounds__(256) void normalize_kernel(const float* __restrict__ x,
                                                        ushort* __restrict__ fn16,
                                                        float* __restrict__ sq) {
    const int row  = blockIdx.x * 4 + (threadIdx.x >> 6);   // 1 wave per row
    const int lane = threadIdx.x & 63;
    float4 v = ((const float4*)(x + (size_t)row * D))[lane];
    float s = v.x * v.x + v.y * v.y + v.z * v.z + v.w * v.w;
    #pragma unroll
    for (int off = 32; off; off >>= 1) s += __shfl_down(s, off);
    s = __shfl(s, 0);
    const float inv = 1.0f / fmaxf(sqrtf(s), 1e-12f);
    v.x *= inv; v.y *= inv; v.z *= inv; v.w *= inv;
    ushort4 b;
    b.x = f2bf(v.x); b.y = f2bf(v.y); b.z = f2bf(v.z); b.w = f2bf(v.w);
    ((ushort4*)(fn16 + (size_t)row * D))[lane] = b;
    // sq from fp32 normalized values (matches reference rounding path)
    float s2 = v.x * v.x + v.y * v.y + v.z * v.z + v.w * v.w;
    #pragma unroll
    for (int off = 32; off; off >>= 1) s2 += __shfl_down(s2, off);
    if (lane == 0) sq[row] = s2;
}

// ---------------- Kernel 2: bf16 MFMA gram + fused batch-hard epilogue ----------------
__global__ __launch_bounds__(256) void gram_kernel(const ushort* __restrict__ fn16,
                                                   const float* __restrict__ sq,
                                                   const int* __restrict__ lab,
                                                   float* __restrict__ hp_part,
                                                   float* __restrict__ hn_part) {
    __shared__ ushort As[BT][LSTR];
    __shared__ ushort Bs[BT][LSTR];
    __shared__ float  hpL[BT][2];
    __shared__ float  hnL[BT][2];

    const int ib = blockIdx.x / NJB;
    const int jb = blockIdx.x % NJB;
    const int i0 = ib * BT, j0 = jb * BT;

    const int t    = threadIdx.x;
    const int w    = t >> 6;            // wave 0..3
    const int lane = t & 63;
    const int wi   = w >> 1, wj = w & 1; // 2x2 waves, each 64x64
    const int quad = lane >> 4;
    const int l15  = lane & 15;

    floatx4 acc[4][4];
    #pragma unroll
    for (int m = 0; m < 4; m++)
        #pragma unroll
        for (int n = 0; n < 4; n++)
            acc[m][n] = (floatx4){0.f, 0.f, 0.f, 0.f};

    for (int kc = 0; kc < D; kc += BK) {
        __syncthreads();
        // stage A (i-rows) and B (j-rows) chunks, row-major [row][k]
        #pragma unroll
        for (int it = 0; it < 4; it++) {
            const int lin = t + 256 * it;     // 0..1023
            const int c   = lin & 7;          // 16B chunk within row (8 chunks = 64 bf16)
            const int r   = lin >> 3;         // 0..127
            const uint4 a = *(const uint4*)(fn16 + (size_t)(i0 + r) * D + kc + c * 8);
            const uint4 b = *(const uint4*)(fn16 + (size_t)(j0 + r) * D + kc + c * 8);
            *(uint4*)(&As[r][c * 8]) = a;
            *(uint4*)(&Bs[r][c * 8]) = b;
        }
        __syncthreads();
        #pragma unroll
        for (int ks = 0; ks < BK; ks += 32) {
            short8 af[4], bfr[4];
            #pragma unroll
            for (int m = 0; m < 4; m++)
                af[m] = *(const short8*)(&As[wi * 64 + m * 16 + l15][ks + quad * 8]);
            #pragma unroll
            for (int n = 0; n < 4; n++)
                bfr[n] = *(const short8*)(&Bs[wj * 64 + n * 16 + l15][ks + quad * 8]);
            #pragma unroll
            for (int m = 0; m < 4; m++)
                #pragma unroll
                for (int n = 0; n < 4; n++)
                    acc[m][n] = __builtin_amdgcn_mfma_f32_16x16x32_bf16(af[m], bfr[n], acc[m][n], 0, 0, 0);
        }
    }

    // fused epilogue. C/D layout: col=lane&15, row=quad*4+reg.
    float sqj[4]; int labj[4];
    #pragma unroll
    for (int n = 0; n < 4; n++) {
        const int j = j0 + wj * 64 + n * 16 + l15;
        sqj[n] = sq[j]; labj[n] = lab[j];
    }
    #pragma unroll
    for (int m = 0; m < 4; m++) {
        #pragma unroll
        for (int r = 0; r < 4; r++) {
            const int i = i0 + wi * 64 + m * 16 + quad * 4 + r;
            const float sqi = sq[i];
            const int  labi = lab[i];
            float hp = 0.0f, hn = INFINITY;
            #pragma unroll
            for (int n = 0; n < 4; n++) {
                const float g  = acc[m][n][r];
                const float d2 = sqi + sqj[n] - 2.0f * g;
                const float dd = sqrtf(fmaxf(d2, EPS));
                const bool same = (labi == labj[n]);
                hp = fmaxf(hp, same ? dd : 0.0f);
                hn = fminf(hn, same ? INFINITY : dd);
            }
            // reduce across the 16 lanes of this quad (same i-row)
            #pragma unroll
            for (int o = 1; o < 16; o <<= 1) {
                hp = fmaxf(hp, __shfl_xor(hp, o));
                hn = fminf(hn, __shfl_xor(hn, o));
            }
            if (l15 == 0) {
                const int ri = wi * 64 + m * 16 + quad * 4 + r;
                hpL[ri][wj] = hp;
                hnL[ri][wj] = hn;
            }
        }
    }
    __syncthreads();
    if (t < BT) {
        const float hp = fmaxf(hpL[t][0], hpL[t][1]);
        const float hn = fminf(hnL[t][0], hnL[t][1]);
        hp_part[(size_t)jb * N + i0 + t] = hp;
        hn_part[(size_t)jb * N + i0 + t] = hn;
    }
}

// ---------------- Kernel 3a: reduce splits per row, relu, per-block partial sums ----------------
__global__ __launch_bounds__(256) void reduce1_kernel(const float* __restrict__ hp_part,
                                                      const float* __restrict__ hn_part,
                                                      float* __restrict__ partial) {
    const int i = blockIdx.x * 256 + threadIdx.x;   // 32 blocks x 256 = 8192 rows
    float hp = hp_part[i];
    float hn = hn_part[i];
    for (int s = 1; s < NJB; s++) {
        hp = fmaxf(hp, hp_part[(size_t)s * N + i]);
        hn = fminf(hn, hn_part[(size_t)s * N + i]);
    }
    const float l = hp - hn + MARGIN;
    float sum = (l > 0.0f) ? l : 0.0f;
    #pragma unroll
    for (int off = 32; off; off >>= 1) sum += __shfl_down(sum, off);
    __shared__ float ws[4];
    if ((threadIdx.x & 63) == 0) ws[threadIdx.x >> 6] = sum;
    __syncthreads();
    if (threadIdx.x == 0) partial[blockIdx.x] = ws[0] + ws[1] + ws[2] + ws[3];
}

// ---------------- Kernel 3b: final sum -> mean ----------------
__global__ __launch_bounds__(64) void reduce2_kernel(const float* __restrict__ partial,
                                                     float* __restrict__ out) {
    float s = (threadIdx.x < 32) ? partial[threadIdx.x] : 0.0f;
    #pragma unroll
    for (int off = 32; off; off >>= 1) s += __shfl_down(s, off);
    if (threadIdx.x == 0) out[0] = s * (1.0f / (float)N);
}

extern "C" void kernel_launch(void* const* d_in, const int* in_sizes, int n_in,
                              void* d_out, int out_size, void* d_ws, size_t ws_size,
                              hipStream_t stream) {
    const float* x   = (const float*)d_in[0];
    const int*   lab = (const int*)d_in[1];
    float* out = (float*)d_out;

    char* ws = (char*)d_ws;
    ushort* fn16 = (ushort*)ws;                                   // N*D bf16 = 4 MB
    float*  sq   = (float*)(ws + (size_t)N * D * 2);              // N floats
    float*  hp   = (float*)(ws + (size_t)N * D * 2 + (size_t)N * 4);
    float*  hn   = hp + (size_t)NJB * N;                          // NJB*N each
    float*  part = hn + (size_t)NJB * N;                          // 32 floats

    normalize_kernel<<<N / 4, 256, 0, stream>>>(x, fn16, sq);
    gram_kernel<<<(N / BT) * NJB, 256, 0, stream>>>(fn16, sq, lab, hp, hn);
    reduce1_kernel<<<N / 256, 256, 0, stream>>>(hp, hn, part);
    reduce2_kernel<<<1, 64, 0, stream>>>(part, out);
}

// Round 3
// 135.626 us; speedup vs baseline: 5.5637x; 1.2334x over previous
//
#include <hip/hip_runtime.h>
#include <hip/hip_bf16.h>
#include <math.h>

#define N 8192
#define D 256
#define MARGIN 0.3f
#define EPS 1e-12f

#define BT 128            // block tile (i and j)
#define BK 64             // K chunk staged in LDS (8 chunks of 8 bf16 = 128 B/row)
#define NJB (N / BT)      // 64 j-blocks

typedef __attribute__((ext_vector_type(8))) short short8;   // 8 bf16 in 4 VGPRs
typedef __attribute__((ext_vector_type(4))) float floatx4;  // MFMA C/D

static __device__ inline ushort f2bf(float f) {
    __hip_bfloat16 h = __float2bfloat16(f);
    return *reinterpret_cast<ushort*>(&h);
}

// async global->LDS, 16B per lane, dest = wave-uniform base + lane*16
static __device__ inline void gload_lds16(const void* g, void* l) {
    __builtin_amdgcn_global_load_lds((const __attribute__((address_space(1))) unsigned int*)g,
                                     (__attribute__((address_space(3))) unsigned int*)l,
                                     16, 0, 0);
}

// ---------------- Kernel 1: L2 normalize rows -> bf16 copy + fp32 sq ----------------
__global__ __launch_bounds__(256) void normalize_kernel(const float* __restrict__ x,
                                                        ushort* __restrict__ fn16,
                                                        float* __restrict__ sq) {
    const int row  = blockIdx.x * 4 + (threadIdx.x >> 6);   // 1 wave per row
    const int lane = threadIdx.x & 63;
    float4 v = ((const float4*)(x + (size_t)row * D))[lane];
    float s = v.x * v.x + v.y * v.y + v.z * v.z + v.w * v.w;
    #pragma unroll
    for (int off = 32; off; off >>= 1) s += __shfl_down(s, off);
    s = __shfl(s, 0);
    const float inv = 1.0f / fmaxf(sqrtf(s), 1e-12f);
    v.x *= inv; v.y *= inv; v.z *= inv; v.w *= inv;
    ushort4 b;
    b.x = f2bf(v.x); b.y = f2bf(v.y); b.z = f2bf(v.z); b.w = f2bf(v.w);
    ((ushort4*)(fn16 + (size_t)row * D))[lane] = b;
    float s2 = v.x * v.x + v.y * v.y + v.z * v.z + v.w * v.w;
    #pragma unroll
    for (int off = 32; off; off >>= 1) s2 += __shfl_down(s2, off);
    if (lane == 0) sq[row] = s2;
}

// ---------------- Kernel 2: bf16 MFMA gram + fused d2 batch-hard epilogue ----------------
// LDS layout: unpadded [row][BK], XOR-swizzled: phys chunk cp holds logical chunk cp^(row&7).
// Staging via global_load_lds (dest contiguous), compute reads land 2 lanes/bank (free).
__global__ __launch_bounds__(256) void gram_kernel(const ushort* __restrict__ fn16,
                                                   const float* __restrict__ sq,
                                                   const int* __restrict__ lab,
                                                   float* __restrict__ hp_part,
                                                   float* __restrict__ hn_part) {
    __shared__ ushort As[BT][BK];     // 16 KB
    __shared__ ushort Bs[BT][BK];     // 16 KB
    __shared__ float  hpL[BT][2];
    __shared__ float  hnL[BT][2];

    const int ib = blockIdx.x / NJB;
    const int jb = blockIdx.x % NJB;
    const int i0 = ib * BT, j0 = jb * BT;

    const int t    = threadIdx.x;
    const int w    = t >> 6;             // wave 0..3
    const int lane = t & 63;
    const int wi   = w >> 1, wj = w & 1; // 2x2 waves, each 64x64
    const int quad = lane >> 4;
    const int l15  = lane & 15;

    floatx4 acc[4][4];
    #pragma unroll
    for (int m = 0; m < 4; m++)
        #pragma unroll
        for (int n = 0; n < 4; n++)
            acc[m][n] = (floatx4){0.f, 0.f, 0.f, 0.f};

    for (int kc = 0; kc < D; kc += BK) {
        __syncthreads();
        // stage A and B chunks: slot s = q*256 + w*64 + lane; r = s>>3, phys chunk = s&7
        #pragma unroll
        for (int q = 0; q < 4; q++) {
            const int s  = q * 256 + w * 64 + lane;
            const int r  = s >> 3;
            const int cl = (s & 7) ^ (r & 7);           // logical chunk for this phys slot
            const ushort* ga = fn16 + (size_t)(i0 + r) * D + kc + cl * 8;
            const ushort* gb = fn16 + (size_t)(j0 + r) * D + kc + cl * 8;
            const int base = (q * 256 + w * 64) * 8;    // ushort offset of wave's slot 0
            gload_lds16(ga, (ushort*)As + base);
            gload_lds16(gb, (ushort*)Bs + base);
        }
        __syncthreads();
        #pragma unroll
        for (int ks = 0; ks < 2; ks++) {                // logical chunk base = ks*4 + quad
            short8 af[4], bfr[4];
            #pragma unroll
            for (int m = 0; m < 4; m++) {
                const int r  = wi * 64 + m * 16 + l15;
                const int cp = (ks * 4 + quad) ^ (r & 7);
                af[m] = *(const short8*)(&As[r][cp * 8]);
            }
            #pragma unroll
            for (int n = 0; n < 4; n++) {
                const int r  = wj * 64 + n * 16 + l15;
                const int cp = (ks * 4 + quad) ^ (r & 7);
                bfr[n] = *(const short8*)(&Bs[r][cp * 8]);
            }
            #pragma unroll
            for (int m = 0; m < 4; m++)
                #pragma unroll
                for (int n = 0; n < 4; n++)
                    acc[m][n] = __builtin_amdgcn_mfma_f32_16x16x32_bf16(af[m], bfr[n], acc[m][n], 0, 0, 0);
        }
    }

    // fused epilogue on d2 (sqrt deferred: sqrt∘clip is monotone, commutes with max/min)
    // C/D layout: col = l15, row = quad*4 + reg.
    float sqj[4]; int labj[4];
    #pragma unroll
    for (int n = 0; n < 4; n++) {
        const int j = j0 + wj * 64 + n * 16 + l15;
        sqj[n] = sq[j]; labj[n] = lab[j];
    }
    #pragma unroll
    for (int m = 0; m < 4; m++) {
        #pragma unroll
        for (int r = 0; r < 4; r++) {
            const int i = i0 + wi * 64 + m * 16 + quad * 4 + r;
            const float sqi = sq[i];
            const int  labi = lab[i];
            float hp = -INFINITY, hn = INFINITY;
            #pragma unroll
            for (int n = 0; n < 4; n++) {
                const float d2 = fmaf(-2.0f, acc[m][n][r], sqi + sqj[n]);
                const bool same = (labi == labj[n]);
                hp = fmaxf(hp, same ? d2 : -INFINITY);
                hn = fminf(hn, same ? INFINITY : d2);
            }
            #pragma unroll
            for (int o = 1; o < 16; o <<= 1) {
                hp = fmaxf(hp, __shfl_xor(hp, o));
                hn = fminf(hn, __shfl_xor(hn, o));
            }
            if (l15 == 0) {
                const int ri = wi * 64 + m * 16 + quad * 4 + r;
                hpL[ri][wj] = hp;
                hnL[ri][wj] = hn;
            }
        }
    }
    __syncthreads();
    if (t < BT) {
        hp_part[(size_t)jb * N + i0 + t] = fmaxf(hpL[t][0], hpL[t][1]);
        hn_part[(size_t)jb * N + i0 + t] = fminf(hnL[t][0], hnL[t][1]);
    }
}

// ---------------- Kernel 3: reduce splits, sqrt, relu, mean (atomic accumulate) ----------------
__global__ __launch_bounds__(256) void reduce_kernel(const float* __restrict__ hp_part,
                                                     const float* __restrict__ hn_part,
                                                     float* __restrict__ out) {
    const int i = blockIdx.x * 256 + threadIdx.x;   // 32 blocks x 256 = 8192 rows
    float hp = hp_part[i];
    float hn = hn_part[i];
    for (int s = 1; s < NJB; s++) {
        hp = fmaxf(hp, hp_part[(size_t)s * N + i]);
        hn = fminf(hn, hn_part[(size_t)s * N + i]);
    }
    const float dp = sqrtf(fmaxf(hp, EPS));
    const float dn = sqrtf(fmaxf(hn, EPS));
    const float l  = dp - dn + MARGIN;
    float sum = (l > 0.0f) ? l : 0.0f;
    #pragma unroll
    for (int off = 32; off; off >>= 1) sum += __shfl_down(sum, off);
    __shared__ float wsum[4];
    if ((threadIdx.x & 63) == 0) wsum[threadIdx.x >> 6] = sum;
    __syncthreads();
    if (threadIdx.x == 0)
        atomicAdd(out, (wsum[0] + wsum[1] + wsum[2] + wsum[3]) * (1.0f / (float)N));
}

extern "C" void kernel_launch(void* const* d_in, const int* in_sizes, int n_in,
                              void* d_out, int out_size, void* d_ws, size_t ws_size,
                              hipStream_t stream) {
    const float* x   = (const float*)d_in[0];
    const int*   lab = (const int*)d_in[1];
    float* out = (float*)d_out;

    char* ws = (char*)d_ws;
    ushort* fn16 = (ushort*)ws;                                   // N*D bf16 = 4 MB
    float*  sq   = (float*)(ws + (size_t)N * D * 2);              // N floats
    float*  hp   = (float*)(ws + (size_t)N * D * 2 + (size_t)N * 4);
    float*  hn   = hp + (size_t)NJB * N;                          // NJB*N each (d2 partials)

    hipMemsetAsync(out, 0, sizeof(float), stream);
    normalize_kernel<<<N / 4, 256, 0, stream>>>(x, fn16, sq);
    gram_kernel<<<(N / BT) * NJB, 256, 0, stream>>>(fn16, sq, lab, hp, hn);
    reduce_kernel<<<N / 256, 256, 0, stream>>>(hp, hn, out);
}